// Round 11
// baseline (106.136 us; speedup 1.0000x reference)
//
#include <hip/hip_runtime.h>
#include <math.h>

#define B_SZ 2048
#define R_SZ 64
#define TS 64                    // tile edge
#define NTILE 32                 // 2048/64
#define NBLK (NTILE + NTILE * (NTILE - 1) / 2)   // 32 diag + 496 pairs = 528

#define B_POW_NEG02 0.217637640824031f   // 2048^-0.2 = 2^-2.2
#define SQRT_2PI 2.5066282746310002f
#define LOG2E 1.44269504088896340736f

extern "C" __device__ float __ocml_native_exp2_f32(float);

typedef __attribute__((ext_vector_type(2))) float f32x2;

// ---------------------------------------------------------------------------
// ws layout (floats):
//   [0:64)    lscale        = 1/(B*h*sqrt(2pi))
//   [64:128)  cov_partial
//   [160]     ent_acc       (own line)
//   [192]     done2         (int, own line)
//   [256:131328)            U = kscale[r]*A   (prescaled, 512 KB)
//   [131328:+4194304)       P[32][32][64][64] partial-density slots (16.8 MB)
//     P[a][c] for c>a : row sums of tile-pair block (a,c)
//     P[a][a]          : row sums of diag block a (includes self term)
//     P[a][c] for c<a : col sums of tile-pair block (c,a)
//   Every slot written exactly once -> no zeroing, no atomics.
// ---------------------------------------------------------------------------

// Kernel 1: stats + Gram row + cov row + U prescale + flag init.
__global__ __launch_bounds__(1024) void cov_stats_kernel(const float* __restrict__ A,
                                                         float* __restrict__ U,
                                                         float* __restrict__ lscale,
                                                         float* __restrict__ cov_partial,
                                                         float* __restrict__ ent_acc,
                                                         int* __restrict__ done2) {
    int i = blockIdx.x;
    int tid = threadIdx.x;
    int j = tid & 63, bg = tid >> 6;          // 16 b-groups

    float g = 0.f, sj = 0.f, s2j = 0.f;
#pragma unroll 4
    for (int b = bg; b < B_SZ; b += 16) {
        float ai = A[b * R_SZ + i];           // wave-uniform broadcast
        float aj = A[b * R_SZ + j];           // coalesced
        g = fmaf(ai, aj, g);
        sj += aj;
        s2j = fmaf(aj, aj, s2j);
    }

    __shared__ float gred[16][64], sred[16][64], s2red[16][64];
    __shared__ float gfin[64], sfin[64], hs[64];
    gred[bg][j] = g; sred[bg][j] = sj; s2red[bg][j] = s2j;
    __syncthreads();
    if (tid < 64) {
        float G = 0.f, S = 0.f, S2 = 0.f;
#pragma unroll
        for (int t = 0; t < 16; ++t) { G += gred[t][j]; S += sred[t][j]; S2 += s2red[t][j]; }
        gfin[j] = G;
        sfin[j] = S;
        float m = S * (1.f / (float)B_SZ);
        float var = (S2 - S * m) * (1.f / (float)(B_SZ - 1));   // ddof=1
        var = fmaxf(var, 0.f);
        float h = fmaxf(1.06f * sqrtf(var) * B_POW_NEG02, 1e-4f);
        hs[j] = sqrtf(0.5f * LOG2E) / h;      // exp2(-(k*d)^2) = exp(-0.5(d/h)^2)
        if (i == 0) lscale[j] = 1.0f / ((float)B_SZ * h * SQRT_2PI);
    }
    __syncthreads();
    if (tid < 64) {                            // covariance row i
        float m_j = sfin[j] * (1.f / (float)B_SZ);
        float m_i = sfin[i] * (1.f / (float)B_SZ);
        float cov = (gfin[j] - (float)B_SZ * m_i * m_j) * (1.f / (float)(B_SZ - 1));
        float v = (j == i) ? 0.f : cov * cov;
        for (int off = 32; off > 0; off >>= 1) v += __shfl_down(v, off, 64);
        if (j == 0) cov_partial[i] = v;
    }
    if (i == 0 && tid == 64) { *ent_acc = 0.f; *done2 = 0; }

    // prescale U rows [i*32, i*32+32): 2048 elems, 2 per thread (coalesced)
    int base = i * (32 * R_SZ);
    float k0 = hs[tid & 63];
    U[base + tid]        = A[base + tid]        * k0;
    U[base + 1024 + tid] = A[base + 1024 + tid] * k0;
}

// ---------------------------------------------------------------------------
// Kernel 2: symmetric KDE, barrier-stepped systolic. 528 blocks x 1024 thr.
// Off-diag block (ti<tj): wave w owns q rows {w,w+16,w+32,w+48} (register
// row sums). 16 steps; at step k wave w EXCLUSIVELY owns s-subtile
// (w+k)&15 (4 s-rows) -> colbuf RMW is plain LDS ops, race-free by barrier.
// Step 0 writes (no read) -> no colbuf zeroing. Diag block: plain 64-s
// sweep, rows only (includes the s==q self term). Flushes are plain global
// stores into private P slots. NO atomics anywhere.
// ---------------------------------------------------------------------------
__global__ __launch_bounds__(1024, 8) void kde_sym_kernel(const float* __restrict__ U,
                                                          float* __restrict__ P) {
    __shared__ float Ls[TS][R_SZ];       // 16 KB  (bank = r%32 -> 2-way, free)
    __shared__ float colbuf[TS][R_SZ];   // 16 KB

    int tid = threadIdx.x;
    int r = tid & 63, w = tid >> 6;

    // decode tile-pair: t<32 -> diag tile t; else upper-triangle (ti<tj)
    int t = blockIdx.x;
    int ti, tj;
    bool diag;
    if (t < NTILE) {
        ti = tj = t; diag = true;
    } else {
        int p = t - NTILE; diag = false;
        ti = 0;
        int cnt = NTILE - 1;
        while (p >= cnt) { p -= cnt; ti++; cnt--; }
        tj = ti + 1 + p;
    }
    int q0 = ti * TS, s0 = tj * TS;

    // stage s-tile (1 float4/thread = 16 KB)
    {
        const float4* src = (const float4*)(U + s0 * R_SZ);
        float4* dst = (float4*)&Ls[0][0];
        dst[tid] = src[tid];
    }
    f32x2 uq01 = { U[(q0 + w +  0) * R_SZ + r], U[(q0 + w + 16) * R_SZ + r] };
    f32x2 uq23 = { U[(q0 + w + 32) * R_SZ + r], U[(q0 + w + 48) * R_SZ + r] };
    f32x2 r01 = {0.f, 0.f}, r23 = {0.f, 0.f};
    __syncthreads();

#define ROWCOL_BODY(S_IDX, CC)                                                 \
    {                                                                          \
        float us = Ls[(S_IDX)][r];                                             \
        f32x2 uss = { us, us };                                                \
        f32x2 d01 = uq01 - uss, d23 = uq23 - uss;                              \
        f32x2 n01 = -d01 * d01, n23 = -d23 * d23;                              \
        f32x2 e01 = { __ocml_native_exp2_f32(n01.x), __ocml_native_exp2_f32(n01.y) }; \
        f32x2 e23 = { __ocml_native_exp2_f32(n23.x), __ocml_native_exp2_f32(n23.y) }; \
        r01 += e01; r23 += e23;                                                \
        CC = e01 + e23;                                                        \
    }

    if (diag) {
        f32x2 sink;
#pragma unroll 8
        for (int s = 0; s < TS; ++s) ROWCOL_BODY(s, sink);   // rows only
        (void)sink;
    } else {
#pragma unroll 1
        for (int k = 0; k < 16; ++k) {
            int sb = 4 * ((w + k) & 15);       // exclusively-owned s-subtile
            f32x2 cc0, cc1, cc2, cc3;
            ROWCOL_BODY(sb + 0, cc0);
            ROWCOL_BODY(sb + 1, cc1);
            ROWCOL_BODY(sb + 2, cc2);
            ROWCOL_BODY(sb + 3, cc3);
            if (k == 0) {                      // first touch: write, no read
                colbuf[sb + 0][r] = cc0.x + cc0.y;
                colbuf[sb + 1][r] = cc1.x + cc1.y;
                colbuf[sb + 2][r] = cc2.x + cc2.y;
                colbuf[sb + 3][r] = cc3.x + cc3.y;
            } else {                           // plain RMW — sole writer
                colbuf[sb + 0][r] += cc0.x + cc0.y;
                colbuf[sb + 1][r] += cc1.x + cc1.y;
                colbuf[sb + 2][r] += cc2.x + cc2.y;
                colbuf[sb + 3][r] += cc3.x + cc3.y;
            }
            __syncthreads();                   // hand ownership to next wave
        }
    }
#undef ROWCOL_BODY

    // row flush -> P[ti][tj] (plain stores, slot private to this block)
    float* rowp = P + (size_t)(ti * NTILE + tj) * (TS * R_SZ);
    rowp[(w +  0) * R_SZ + r] = r01.x;
    rowp[(w + 16) * R_SZ + r] = r01.y;
    rowp[(w + 32) * R_SZ + r] = r23.x;
    rowp[(w + 48) * R_SZ + r] = r23.y;

    if (!diag) {                               // col flush -> P[tj][ti]
        float* colp = P + (size_t)(tj * NTILE + ti) * (TS * R_SZ);
#pragma unroll
        for (int i2 = 0; i2 < 4; ++i2) {
            int srow = w + 16 * i2;
            colp[srow * R_SZ + r] = colbuf[srow][r];
        }
    }
}

// ---------------------------------------------------------------------------
// Kernel 3: assemble density from P (sum of 32 slots per row) + entropy +
// grid-final fold. 64 blocks x 1024; wave sg handles 2 density rows.
// ---------------------------------------------------------------------------
__global__ __launch_bounds__(1024) void entropy_kernel(const float* __restrict__ P,
                                                       const float* __restrict__ lscale,
                                                       const float* __restrict__ cov_partial,
                                                       float* __restrict__ ent_acc,
                                                       int* __restrict__ done2,
                                                       float* __restrict__ out) {
    int tid = threadIdx.x;
    int r = tid & 63, sg = tid >> 6;
    float ls = lscale[r];
    float v = 0.f;
#pragma unroll
    for (int rr = 0; rr < 2; ++rr) {
        int b = blockIdx.x * 32 + sg * 2 + rr;
        int a = b >> 6, row = b & 63;
        const float* base = P + (size_t)(a * NTILE) * (TS * R_SZ) + row * R_SZ + r;
        float S = 0.f;
#pragma unroll
        for (int c = 0; c < NTILE; ++c) S += base[(size_t)c * (TS * R_SZ)];
        v += __logf(fmaf(S, ls, 1e-8f));
    }
    for (int off = 32; off > 0; off >>= 1) v += __shfl_down(v, off, 64);
    __shared__ float wr[16];
    if (r == 0) wr[sg] = v;
    __syncthreads();
    __shared__ int lastflag;
    if (tid == 0) {
        float s = 0.f;
#pragma unroll
        for (int ww = 0; ww < 16; ++ww) s += wr[ww];
        atomicAdd(ent_acc, s);             // once per block (CAS fine here)
        __threadfence();
        int prev = atomicAdd(done2, 1);
        lastflag = (prev == 63);
    }
    __syncthreads();
    if (lastflag && tid < 64) {            // grid-final fold in last block
        __threadfence();
        float v2 = cov_partial[tid];
        for (int off = 32; off > 0; off >>= 1) v2 += __shfl_down(v2, off, 64);
        if (tid == 0) {
            float ent = __hip_atomic_load(ent_acc, __ATOMIC_ACQUIRE,
                                          __HIP_MEMORY_SCOPE_AGENT);
            out[0] = ent * (1.0f / ((float)B_SZ * (float)R_SZ)) + v2;
        }
    }
}

extern "C" void kernel_launch(void* const* d_in, const int* in_sizes, int n_in,
                              void* d_out, int out_size, void* d_ws, size_t ws_size,
                              hipStream_t stream) {
    const float* A = (const float*)d_in[0];
    float* out = (float*)d_out;

    float* wsf = (float*)d_ws;
    float* lscale      = wsf;                 // 64
    float* cov_partial = wsf + 64;            // 64
    float* ent_acc     = wsf + 160;           // isolated line
    int*   done2       = (int*)(wsf + 192);
    float* U           = wsf + 256;           // 2048*64
    float* P           = wsf + 256 + B_SZ * R_SZ;   // 32*32*64*64 floats

    cov_stats_kernel<<<R_SZ, 1024, 0, stream>>>(A, U, lscale, cov_partial,
                                                ent_acc, done2);
    kde_sym_kernel<<<NBLK, 1024, 0, stream>>>(U, P);
    entropy_kernel<<<64, 1024, 0, stream>>>(P, lscale, cov_partial,
                                            ent_acc, done2, out);
}

// Round 12
// 100.241 us; speedup vs baseline: 1.0588x; 1.0588x over previous
//
#include <hip/hip_runtime.h>
#include <math.h>

#define B_SZ 2048
#define R_SZ 64
#define QT 8                    // q rows per kde block
#define KDE_BLOCKS (B_SZ / QT)  // 256 blocks x 16 waves

#define B_POW_NEG02 0.217637640824031f   // 2048^-0.2 = 2^-2.2
#define SQRT_2PI 2.5066282746310002f
#define LOG2E 1.44269504088896340736f

// native v_exp_f32 (exp2)
extern "C" __device__ float __ocml_native_exp2_f32(float);

typedef __attribute__((ext_vector_type(2))) float f32x2;  // -> v_pk_* f32 ops

// ---------------------------------------------------------------------------
// ws layout (floats):
//   [0:64)    cov_partial   (plain store per epilogue block)
//   [96]      ent_acc       (own line)
//   [128]     done2         (int, own line)
//   [256:256+131072)  density[2048][64]  (plain stores, exclusive rows)
// Total ~516 KB — smaller ws => shorter harness poison-fill.
// ---------------------------------------------------------------------------

// Kernel 1: fused stats + pairwise KDE. 256 blocks x 1024 thr.
// Per-block redundant column stats (deterministic, ~0.4us) -> kscale[r] in
// LDS; main loop = R9's 8-deep register prefetch pipeline with the ×k mul
// folded into the load path. Density rows written with PLAIN stores
// (block exclusively owns q-rows [8b, 8b+8)). No atomics, no zeroing.
__global__ __launch_bounds__(1024) void kde_fused_kernel(const float* __restrict__ A,
                                                         float* __restrict__ density,
                                                         float* __restrict__ ent_acc,
                                                         int* __restrict__ done2) {
    int tid = threadIdx.x;
    int r = tid & 63, sg = tid >> 6;

    // ---- per-block column stats: wave sg covers rows [128*sg, 128*sg+128) ----
    float s = 0.f, s2 = 0.f;
    {
        const float* Ac = A + sg * (128 * R_SZ) + r;
#pragma unroll 8
        for (int b = 0; b < 128; ++b) {
            float v = Ac[b * R_SZ];
            s += v;
            s2 = fmaf(v, v, s2);
        }
    }
    __shared__ float sred[16][64], s2red[16][64];
    __shared__ float ksh[64];
    sred[sg][r] = s; s2red[sg][r] = s2;
    __syncthreads();
    if (tid < 64) {                       // wave 0, lane r = tid
        float S = 0.f, S2 = 0.f;
#pragma unroll
        for (int t = 0; t < 16; ++t) { S += sred[t][tid]; S2 += s2red[t][tid]; }
        float m = S * (1.f / (float)B_SZ);
        float var = (S2 - S * m) * (1.f / (float)(B_SZ - 1));   // ddof=1
        var = fmaxf(var, 0.f);
        float h = fmaxf(1.06f * sqrtf(var) * B_POW_NEG02, 1e-4f);
        ksh[tid] = sqrtf(0.5f * LOG2E) / h;   // exp2(-(k*d)^2) = exp(-0.5(d/h)^2)
    }
    if (blockIdx.x == 0 && tid == 64) { *ent_acc = 0.f; *done2 = 0; }
    __syncthreads();
    float k = ksh[r];

    // ---- q fragments ----
    int q0 = blockIdx.x * QT;
    f32x2 uq01 = { A[(q0 + 0) * R_SZ + r] * k, A[(q0 + 1) * R_SZ + r] * k };
    f32x2 uq23 = { A[(q0 + 2) * R_SZ + r] * k, A[(q0 + 3) * R_SZ + r] * k };
    f32x2 uq45 = { A[(q0 + 4) * R_SZ + r] * k, A[(q0 + 5) * R_SZ + r] * k };
    f32x2 uq67 = { A[(q0 + 6) * R_SZ + r] * k, A[(q0 + 7) * R_SZ + r] * k };
    f32x2 c01 = { 0.f, 0.f }, c23 = { 0.f, 0.f };
    f32x2 c45 = { 0.f, 0.f }, c67 = { 0.f, 0.f };

#define KDE_BODY(usv)                                                          \
    {                                                                          \
        f32x2 uss = { (usv), (usv) };                                          \
        f32x2 d01 = uq01 - uss, d23 = uq23 - uss;                              \
        f32x2 d45 = uq45 - uss, d67 = uq67 - uss;                              \
        f32x2 n01 = -d01 * d01, n23 = -d23 * d23;                              \
        f32x2 n45 = -d45 * d45, n67 = -d67 * d67;                              \
        f32x2 e01 = { __ocml_native_exp2_f32(n01.x), __ocml_native_exp2_f32(n01.y) }; \
        f32x2 e23 = { __ocml_native_exp2_f32(n23.x), __ocml_native_exp2_f32(n23.y) }; \
        f32x2 e45 = { __ocml_native_exp2_f32(n45.x), __ocml_native_exp2_f32(n45.y) }; \
        f32x2 e67 = { __ocml_native_exp2_f32(n67.x), __ocml_native_exp2_f32(n67.y) }; \
        c01 += e01; c23 += e23; c45 += e45; c67 += e67;                        \
    }

    // wave sg consumes s = sg + 16k, k = 0..127 (elem stride 16*64 = 1024)
    const float* Up = A + sg * R_SZ + r;
    float p[8];
#pragma unroll
    for (int jj = 0; jj < 8; ++jj) p[jj] = Up[jj * 1024];   // 8 in flight

    int li = 8 * 1024;
#pragma unroll 1
    for (int kk = 0; kk < 15; ++kk) {                       // 15 x 8 = 120
#pragma unroll
        for (int jj = 0; jj < 8; ++jj) {
            float us = p[jj] * k;
            p[jj] = Up[li + jj * 1024];                     // prefetch ahead
            KDE_BODY(us);
        }
        li += 8 * 1024;
    }
#pragma unroll
    for (int jj = 0; jj < 8; ++jj) {                        // drain last 8
        float us = p[jj] * k;
        KDE_BODY(us);
    }
#undef KDE_BODY

    // ---- cross-wave reduction, then PLAIN stores of the 8 owned rows ----
    __shared__ float red[16][QT][64];                       // 32 KB
    red[sg][0][r] = c01.x; red[sg][1][r] = c01.y;
    red[sg][2][r] = c23.x; red[sg][3][r] = c23.y;
    red[sg][4][r] = c45.x; red[sg][5][r] = c45.y;
    red[sg][6][r] = c67.x; red[sg][7][r] = c67.y;
    __syncthreads();
    if (sg < QT) {                                          // wave sg: row q0+sg
        float S = 0.f;
#pragma unroll
        for (int t = 0; t < 16; ++t) S += red[t][sg][r];
        density[(q0 + sg) * R_SZ + r] = S;                  // exclusive row
    }
}

// ---------------------------------------------------------------------------
// Kernel 2: epilogue — Gram row + cov row + lscale + entropy + final fold.
// 64 blocks x 1024. Block i: Gram/cov row i (old cov_stats loop), entropy
// over density rows [32i, 32i+32), done-counter fold -> out[0].
// ---------------------------------------------------------------------------
__global__ __launch_bounds__(1024) void epilogue_kernel(const float* __restrict__ A,
                                                        const float* __restrict__ density,
                                                        float* __restrict__ cov_partial,
                                                        float* __restrict__ ent_acc,
                                                        int* __restrict__ done2,
                                                        float* __restrict__ out) {
    int i = blockIdx.x;
    int tid = threadIdx.x;
    int j = tid & 63, bg = tid >> 6;          // 16 b-groups

    float g = 0.f, sj = 0.f, s2j = 0.f;
#pragma unroll 4
    for (int b = bg; b < B_SZ; b += 16) {
        float ai = A[b * R_SZ + i];           // wave-uniform broadcast
        float aj = A[b * R_SZ + j];           // coalesced
        g = fmaf(ai, aj, g);
        sj += aj;
        s2j = fmaf(aj, aj, s2j);
    }

    __shared__ float gred[16][64], sred[16][64], s2red[16][64];
    __shared__ float gfin[64], sfin[64], lsh[64];
    gred[bg][j] = g; sred[bg][j] = sj; s2red[bg][j] = s2j;
    __syncthreads();
    if (tid < 64) {
        float G = 0.f, S = 0.f, S2 = 0.f;
#pragma unroll
        for (int t = 0; t < 16; ++t) { G += gred[t][j]; S += sred[t][j]; S2 += s2red[t][j]; }
        gfin[j] = G;
        sfin[j] = S;
        float m = S * (1.f / (float)B_SZ);
        float var = (S2 - S * m) * (1.f / (float)(B_SZ - 1));   // ddof=1
        var = fmaxf(var, 0.f);
        float h = fmaxf(1.06f * sqrtf(var) * B_POW_NEG02, 1e-4f);
        lsh[j] = 1.0f / ((float)B_SZ * h * SQRT_2PI);
    }
    __syncthreads();
    if (tid < 64) {                            // covariance row i
        float m_j = sfin[j] * (1.f / (float)B_SZ);
        float m_i = sfin[i] * (1.f / (float)B_SZ);
        float cov = (gfin[j] - (float)B_SZ * m_i * m_j) * (1.f / (float)(B_SZ - 1));
        float v = (j == i) ? 0.f : cov * cov;
        for (int off = 32; off > 0; off >>= 1) v += __shfl_down(v, off, 64);
        if (j == 0) cov_partial[i] = v;
    }

    // entropy over density rows [32i, 32i+32): 2048 elems, 2 per thread
    float ls = lsh[j];
    int f = i * 2048 + tid;
    float v = __logf(fmaf(density[f], ls, 1e-8f))
            + __logf(fmaf(density[f + 1024], ls, 1e-8f));
    for (int off = 32; off > 0; off >>= 1) v += __shfl_down(v, off, 64);
    __shared__ float wr[16];
    if (j == 0) wr[bg] = v;
    __syncthreads();
    __shared__ int lastflag;
    if (tid == 0) {
        float sE = 0.f;
#pragma unroll
        for (int w = 0; w < 16; ++w) sE += wr[w];
        atomicAdd(ent_acc, sE);            // once per block (CAS fine here)
        __threadfence();
        int prev = atomicAdd(done2, 1);
        lastflag = (prev == 63);
    }
    __syncthreads();
    if (lastflag && tid < 64) {            // grid-final fold in last block
        __threadfence();
        float v2 = cov_partial[tid];
        for (int off = 32; off > 0; off >>= 1) v2 += __shfl_down(v2, off, 64);
        if (tid == 0) {
            float ent = __hip_atomic_load(ent_acc, __ATOMIC_ACQUIRE,
                                          __HIP_MEMORY_SCOPE_AGENT);
            out[0] = ent * (1.0f / ((float)B_SZ * (float)R_SZ)) + v2;
        }
    }
}

extern "C" void kernel_launch(void* const* d_in, const int* in_sizes, int n_in,
                              void* d_out, int out_size, void* d_ws, size_t ws_size,
                              hipStream_t stream) {
    const float* A = (const float*)d_in[0];
    float* out = (float*)d_out;

    float* wsf = (float*)d_ws;
    float* cov_partial = wsf;                 // 64
    float* ent_acc     = wsf + 96;            // isolated line
    int*   done2       = (int*)(wsf + 128);
    float* density     = wsf + 256;           // 2048*64

    kde_fused_kernel<<<KDE_BLOCKS, 1024, 0, stream>>>(A, density, ent_acc, done2);
    epilogue_kernel<<<R_SZ, 1024, 0, stream>>>(A, density, cov_partial,
                                               ent_acc, done2, out);
}